// Round 1
// baseline (227.650 us; speedup 1.0000x reference)
//
#include <hip/hip_runtime.h>
#include <hip/hip_bf16.h>

#define B_ 4
#define S_ 4096
#define E_ 512
#define D_ 64

typedef float  f32x4 __attribute__((ext_vector_type(4)));
typedef short  s16x8 __attribute__((ext_vector_type(8)));

// RNE float -> bf16 (as raw short)
__device__ inline short f2bf(float f){
  unsigned u = __builtin_bit_cast(unsigned, f);
  u += 0x7fffu + ((u >> 16) & 1u);
  return (short)(u >> 16);
}
__device__ inline float ex2(float x){ return __builtin_amdgcn_exp2f(x); }

#define QSCALE 0.18033688f  // 0.125 * log2(e)

// ---------------- prep: Wt[192][512] bf16, row n = output col (0..63 Q,64..127 K,128..191 V)
__global__ __launch_bounds__(256) void prep_kernel(const float* __restrict__ Wq,
                                                   const float* __restrict__ Wk,
                                                   const float* __restrict__ Wv,
                                                   short* __restrict__ Wt){
  int t = blockIdx.x * 256 + threadIdx.x;      // 0..98303
  int n = t >> 9, k = t & 511;
  const float* W = (n < 64) ? Wq : (n < 128 ? Wk : Wv);
  float v = W[k * 64 + (n & 63)];
  if (n < 64) v *= QSCALE;                     // fold softmax scale into Q path
  Wt[t] = f2bf(v);
}

// ---------------- proj: X[16384,512]f32 @ Wt^T -> Qb,Kb row-major bf16 ; V stored transposed Vt[B][64][S]
__global__ __launch_bounds__(256) void proj_kernel(const float* __restrict__ X,
                                                   const short* __restrict__ Wt,
                                                   const float* __restrict__ bq,
                                                   const float* __restrict__ bk,
                                                   const float* __restrict__ bv,
                                                   short* __restrict__ Qb,
                                                   short* __restrict__ Kb,
                                                   short* __restrict__ Vt){
  int l = threadIdx.x & 63, w = threadIdx.x >> 6;
  int r0 = (blockIdx.x * 4 + w) * 16;          // 16-row tile, never crosses batch (4096%16==0)
  int g = l >> 4, c = l & 15;

  f32x4 acc[12];
#pragma unroll
  for (int i = 0; i < 12; i++) acc[i] = (f32x4){0.f,0.f,0.f,0.f};

  const float* xp = X + (size_t)(r0 + c) * E_ + g * 8;
  for (int kk = 0; kk < 16; kk++){
    f32x4 a0 = *reinterpret_cast<const f32x4*>(xp + kk * 32);
    f32x4 a1 = *reinterpret_cast<const f32x4*>(xp + kk * 32 + 4);
    s16x8 af;
#pragma unroll
    for (int i = 0; i < 4; i++){ af[i] = f2bf(a0[i]); af[4+i] = f2bf(a1[i]); }
#pragma unroll
    for (int cb = 0; cb < 12; cb++){
      s16x8 bf = *reinterpret_cast<const s16x8*>(Wt + (size_t)(cb * 16 + c) * E_ + kk * 32 + g * 8);
      acc[cb] = __builtin_amdgcn_mfma_f32_16x16x32_bf16(af, bf, acc[cb], 0, 0, 0);
    }
  }

  int b = r0 >> 12;
#pragma unroll
  for (int cb = 0; cb < 12; cb++){
    int col = (cb & 3) * 16 + c;
    float bias = (cb < 4) ? bq[col] * QSCALE : (cb < 8 ? bk[col] : bv[col]);
#pragma unroll
    for (int r = 0; r < 4; r++){
      int row = r0 + g * 4 + r;                // D-frag: row=(lane>>4)*4+reg, col=lane&15 (per 16-col blk)
      short h = f2bf(acc[cb][r] + bias);
      if (cb < 4)      Qb[(size_t)row * D_ + col] = h;
      else if (cb < 8) Kb[(size_t)row * D_ + col] = h;
      else             Vt[((size_t)b * 64 + col) * S_ + (row & (S_ - 1))] = h;
    }
  }
}

// ---------------- attn: flash, causal. 1 block = one 16-query tile; 4 waves split key-tiles mod 4, merge at end.
__global__ __launch_bounds__(256) void attn_kernel(const short* __restrict__ Qb,
                                                   const short* __restrict__ Kb,
                                                   const short* __restrict__ Vt,
                                                   float* __restrict__ out){
  __shared__ float accb[4][64][16];   // 16 KB: per-wave partial O fragments
  __shared__ float mlb[4][64][8];     // 8 KB: per-wave m[4], l[4]
  __shared__ short Pl[4][16][40];     // 5 KB: per-wave P tile (16 rows x 32 keys, pad->40)

  int bid = blockIdx.x;
  int b   = bid >> 8;
  int tl  = 255 - (bid & 255);        // heavy tiles first
  int q0  = tl * 16;
  int l = threadIdx.x & 63, w = threadIdx.x >> 6;
  int g = l >> 4, c = l & 15;

  const short* qp = Qb + ((size_t)(b * S_ + q0 + c)) * D_ + g * 8;
  s16x8 qf0 = *reinterpret_cast<const s16x8*>(qp);
  s16x8 qf1 = *reinterpret_cast<const s16x8*>(qp + 32);

  float m[4], ls[4];
  f32x4 acc[4];
#pragma unroll
  for (int r = 0; r < 4; r++){ m[r] = -1e30f; ls[r] = 0.f; }
#pragma unroll
  for (int d = 0; d < 4; d++) acc[d] = (f32x4){0.f,0.f,0.f,0.f};

  int nkt = (q0 + 47) >> 5;           // ceil((q0+16)/32)
  int row0 = q0 + g * 4;

  for (int kt = w; kt < nkt; kt += 4){
    int k0 = kt * 32;
    const short* kp = Kb + ((size_t)(b * S_ + k0 + c)) * D_ + g * 8;
    s16x8 k00 = *reinterpret_cast<const s16x8*>(kp);
    s16x8 k01 = *reinterpret_cast<const s16x8*>(kp + 32);
    s16x8 k10 = *reinterpret_cast<const s16x8*>(kp + 16 * D_);
    s16x8 k11 = *reinterpret_cast<const s16x8*>(kp + 16 * D_ + 32);

    f32x4 z = (f32x4){0.f,0.f,0.f,0.f};
    f32x4 s0 = __builtin_amdgcn_mfma_f32_16x16x32_bf16(qf0, k00, z, 0, 0, 0);
    s0       = __builtin_amdgcn_mfma_f32_16x16x32_bf16(qf1, k01, s0, 0, 0, 0);
    f32x4 s1 = __builtin_amdgcn_mfma_f32_16x16x32_bf16(qf0, k10, z, 0, 0, 0);
    s1       = __builtin_amdgcn_mfma_f32_16x16x32_bf16(qf1, k11, s1, 0, 0, 0);

    int key0 = k0 + c, key1 = k0 + 16 + c;
    float mx[4];
#pragma unroll
    for (int r = 0; r < 4; r++){
      if (key0 > row0 + r) s0[r] = -1e30f;
      if (key1 > row0 + r) s1[r] = -1e30f;
      mx[r] = fmaxf(s0[r], s1[r]);
    }
#pragma unroll
    for (int off = 8; off >= 1; off >>= 1){
#pragma unroll
      for (int r = 0; r < 4; r++) mx[r] = fmaxf(mx[r], __shfl_xor(mx[r], off));
    }

    float p0[4], p1[4], rs[4], corr[4];
#pragma unroll
    for (int r = 0; r < 4; r++){
      float mn = fmaxf(m[r], mx[r]);
      corr[r] = ex2(m[r] - mn);
      p0[r] = (key0 <= row0 + r) ? ex2(s0[r] - mn) : 0.f;  // explicit 0 for masked (avoid -1e30-(-1e30))
      p1[r] = (key1 <= row0 + r) ? ex2(s1[r] - mn) : 0.f;
      m[r] = mn;
      rs[r] = p0[r] + p1[r];
    }
#pragma unroll
    for (int off = 8; off >= 1; off >>= 1){
#pragma unroll
      for (int r = 0; r < 4; r++) rs[r] += __shfl_xor(rs[r], off);
    }
#pragma unroll
    for (int r = 0; r < 4; r++) ls[r] = ls[r] * corr[r] + rs[r];
#pragma unroll
    for (int d = 0; d < 4; d++)
#pragma unroll
      for (int r = 0; r < 4; r++) acc[d][r] *= corr[r];

    // P (D-layout) -> LDS -> A-layout
#pragma unroll
    for (int r = 0; r < 4; r++){
      Pl[w][g * 4 + r][c]      = f2bf(p0[r]);
      Pl[w][g * 4 + r][c + 16] = f2bf(p1[r]);
    }
    asm volatile("s_waitcnt lgkmcnt(0)" ::: "memory");
    s16x8 pf = *reinterpret_cast<const s16x8*>(&Pl[w][c][g * 8]);

    const short* vp = Vt + ((size_t)(b * 64 + c)) * S_ + k0 + g * 8;
#pragma unroll
    for (int d = 0; d < 4; d++){
      s16x8 vf = *reinterpret_cast<const s16x8*>(vp + (size_t)d * 16 * S_);
      acc[d] = __builtin_amdgcn_mfma_f32_16x16x32_bf16(pf, vf, acc[d], 0, 0, 0);
    }
  }

  // merge the 4 waves' partial (m,l,acc)
#pragma unroll
  for (int d = 0; d < 4; d++)
#pragma unroll
    for (int r = 0; r < 4; r++) accb[w][l][d * 4 + r] = acc[d][r];
#pragma unroll
  for (int r = 0; r < 4; r++){ mlb[w][l][r] = m[r]; mlb[w][l][4 + r] = ls[r]; }
  __syncthreads();

  float ms[4], lt[4] = {0.f,0.f,0.f,0.f}, o[4] = {0.f,0.f,0.f,0.f};
#pragma unroll
  for (int r = 0; r < 4; r++){
    ms[r] = mlb[0][l][r];
#pragma unroll
    for (int j = 1; j < 4; j++) ms[r] = fmaxf(ms[r], mlb[j][l][r]);
  }
#pragma unroll
  for (int j = 0; j < 4; j++){
#pragma unroll
    for (int r = 0; r < 4; r++){
      float wj = ex2(mlb[j][l][r] - ms[r]);
      lt[r] += mlb[j][l][4 + r] * wj;
      o[r]  += accb[j][l][w * 4 + r] * wj;   // this wave finalizes d-block w
    }
  }
#pragma unroll
  for (int r = 0; r < 4; r++)
    out[((size_t)(b * S_ + q0 + g * 4 + r)) * D_ + w * 16 + c] = o[r] / lt[r];
}

extern "C" void kernel_launch(void* const* d_in, const int* in_sizes, int n_in,
                              void* d_out, int out_size, void* d_ws, size_t ws_size,
                              hipStream_t stream){
  const float* X  = (const float*)d_in[0];
  const float* Wq = (const float*)d_in[1];
  const float* bq = (const float*)d_in[2];
  const float* Wk = (const float*)d_in[3];
  const float* bk = (const float*)d_in[4];
  const float* Wv = (const float*)d_in[5];
  const float* bv = (const float*)d_in[6];
  float* out = (float*)d_out;

  char* base = (char*)d_ws;
  short* Wt = (short*)(base);                    // 192*512*2      = 196608
  short* Qb = (short*)(base + 196608);           // 16384*64*2     = 2097152
  short* Kb = (short*)(base + 196608 + 2097152);
  short* Vt = (short*)(base + 196608 + 2 * 2097152);

  prep_kernel<<<384, 256, 0, stream>>>(Wq, Wk, Wv, Wt);
  proj_kernel<<<256, 256, 0, stream>>>(X, Wt, bq, bk, bv, Qb, Kb, Vt);
  attn_kernel<<<1024, 256, 0, stream>>>(Qb, Kb, Vt, out);
}

// Round 2
// 181.313 us; speedup vs baseline: 1.2556x; 1.2556x over previous
//
#include <hip/hip_runtime.h>
#include <hip/hip_bf16.h>

#define B_ 4
#define S_ 4096
#define E_ 512
#define D_ 64

typedef float  f32x4  __attribute__((ext_vector_type(4)));
typedef float  f32x16 __attribute__((ext_vector_type(16)));
typedef short  s16x8  __attribute__((ext_vector_type(8)));

__device__ inline short f2bf(float f){
  unsigned u = __builtin_bit_cast(unsigned, f);
  u += 0x7fffu + ((u >> 16) & 1u);
  return (short)(u >> 16);
}
__device__ inline unsigned bfpack(float a, float b){
  unsigned ua = __builtin_bit_cast(unsigned, a);
  unsigned ub = __builtin_bit_cast(unsigned, b);
  ua += 0x7fffu + ((ua >> 16) & 1u);
  ub += 0x7fffu + ((ub >> 16) & 1u);
  return (ua >> 16) | (ub & 0xffff0000u);
}
__device__ inline float ex2(float x){ return __builtin_amdgcn_exp2f(x); }

#define QSCALE 0.18033688f  // 0.125 * log2(e): softmax in exp2 domain, folded into Q

// ---------------- prep: Wt[192][512] bf16 (row n = output col; 0..63 Q, 64..127 K, 128..191 V)
__global__ __launch_bounds__(256) void prep_kernel(const float* __restrict__ Wq,
                                                   const float* __restrict__ Wk,
                                                   const float* __restrict__ Wv,
                                                   short* __restrict__ Wt){
  int t = blockIdx.x * 256 + threadIdx.x;      // 0..98303
  int n = t >> 9, k = t & 511;
  const float* W = (n < 64) ? Wq : (n < 128 ? Wk : Wv);
  float v = W[k * 64 + (n & 63)];
  if (n < 64) v *= QSCALE;
  Wt[t] = f2bf(v);
}

// ---------------- proj: 1024 blocks, 1 block = 16-row tile; 4 waves split 192 cols (48 each).
__global__ __launch_bounds__(256) void proj_kernel(const float* __restrict__ X,
                                                   const short* __restrict__ Wt,
                                                   const float* __restrict__ bq,
                                                   const float* __restrict__ bk,
                                                   const float* __restrict__ bv,
                                                   short* __restrict__ Qb,
                                                   short* __restrict__ Kb,
                                                   short* __restrict__ Vt){
  int l = threadIdx.x & 63, w = threadIdx.x >> 6;
  int r0 = blockIdx.x * 16;
  int g = l >> 4, c = l & 15;

  f32x4 acc[3];
#pragma unroll
  for (int j = 0; j < 3; j++) acc[j] = (f32x4){0.f,0.f,0.f,0.f};

  const float* xp = X + (size_t)(r0 + c) * E_ + g * 8;
  const short* wp = Wt + (size_t)(w * 48 + c) * E_ + g * 8;

  for (int kk = 0; kk < 16; kk++){
    f32x4 a0 = *reinterpret_cast<const f32x4*>(xp + kk * 32);
    f32x4 a1 = *reinterpret_cast<const f32x4*>(xp + kk * 32 + 4);
    s16x8 af;
#pragma unroll
    for (int i = 0; i < 4; i++){ af[i] = f2bf(a0[i]); af[4+i] = f2bf(a1[i]); }
#pragma unroll
    for (int j = 0; j < 3; j++){
      s16x8 bf = *reinterpret_cast<const s16x8*>(wp + (size_t)j * 16 * E_ + kk * 32);
      acc[j] = __builtin_amdgcn_mfma_f32_16x16x32_bf16(af, bf, acc[j], 0, 0, 0);
    }
  }

  int b = r0 >> 12;
#pragma unroll
  for (int j = 0; j < 3; j++){
    int cbi = w * 3 + j;
    int col = ((cbi & 3) << 4) + c;
    float bias = (cbi < 4) ? bq[col] * QSCALE : (cbi < 8 ? bk[col] : bv[col]);
#pragma unroll
    for (int r = 0; r < 4; r++){
      int row = r0 + g * 4 + r;                // D-frag: row=(lane>>4)*4+reg, col=lane&15
      short h = f2bf(acc[j][r] + bias);
      if (cbi < 4)      Qb[(size_t)row * D_ + col] = h;
      else if (cbi < 8) Kb[(size_t)row * D_ + col] = h;
      else              Vt[((size_t)(b * 64 + col)) * S_ + (row & (S_ - 1))] = h;
    }
  }
}

// ---------------- attn: 32x32 swapped-QK^T flash. 512 blocks (b,tile) x 8 waves (keys mod 8).
// Lane owns query col (lo=l&31); hi pair splits the 32 keys per tile. Softmax lane-local.
__global__ __launch_bounds__(512, 4) void attn_kernel(const short* __restrict__ Qb,
                                                      const short* __restrict__ Kb,
                                                      const short* __restrict__ Vt,
                                                      float* __restrict__ out){
  __shared__ float accw[8][32][64];   // 64 KB: per-wave partial O (f32)
  __shared__ float mlw[8][32][2];     // 2 KB: per-wave (m, l) per query
  __shared__ float corrw[8][32];      // 1 KB: rescale-factor bounce (rare path)

  const int tid = threadIdx.x;
  const int w  = tid >> 6;
  const int l  = tid & 63;
  const int lo = l & 31, hi = l >> 5;
  const int bid = blockIdx.x;
  const int b  = bid >> 7;
  const int t  = 127 - (bid & 127);   // heavy tiles first
  const int q0 = t << 5;

  const short* qp = Qb + ((size_t)((b << 12) + q0 + lo)) * D_ + hi * 8;
  s16x8 qf0 = *reinterpret_cast<const s16x8*>(qp);
  s16x8 qf1 = *reinterpret_cast<const s16x8*>(qp + 16);
  s16x8 qf2 = *reinterpret_cast<const s16x8*>(qp + 32);
  s16x8 qf3 = *reinterpret_cast<const s16x8*>(qp + 48);

  float m = -1e30f, ls = 0.f;
  f32x16 acc0, acc1;
#pragma unroll
  for (int r = 0; r < 16; r++){ acc0[r] = 0.f; acc1[r] = 0.f; }

  const int nkt = t + 1;
  for (int kt = w; kt < nkt; kt += 8){
    const int k0 = kt << 5;
    const short* kp = Kb + ((size_t)((b << 12) + k0 + lo)) * D_ + hi * 8;
    s16x8 kf0 = *reinterpret_cast<const s16x8*>(kp);
    s16x8 kf1 = *reinterpret_cast<const s16x8*>(kp + 16);
    s16x8 kf2 = *reinterpret_cast<const s16x8*>(kp + 32);
    s16x8 kf3 = *reinterpret_cast<const s16x8*>(kp + 48);

    f32x16 s;
#pragma unroll
    for (int r = 0; r < 16; r++) s[r] = 0.f;
    s = __builtin_amdgcn_mfma_f32_32x32x16_bf16(kf0, qf0, s, 0, 0, 0);
    s = __builtin_amdgcn_mfma_f32_32x32x16_bf16(kf1, qf1, s, 0, 0, 0);
    s = __builtin_amdgcn_mfma_f32_32x32x16_bf16(kf2, qf2, s, 0, 0, 0);
    s = __builtin_amdgcn_mfma_f32_32x32x16_bf16(kf3, qf3, s, 0, 0, 0);
    // D: col(lane&31)=query, row=(r&3)+8*(r>>2)+4*hi = key offset

    if (k0 == q0){                     // only the diagonal tile needs masking
#pragma unroll
      for (int r = 0; r < 16; r++){
        int key = k0 + (r & 3) + ((r >> 2) << 3) + (hi << 2);
        if (key > q0 + lo) s[r] = -1e30f;
      }
    }

    // lane-local row max (16 regs) + pair exchange
    float x0 = fmaxf(s[0], s[1]),  x1 = fmaxf(s[2], s[3]);
    float x2 = fmaxf(s[4], s[5]),  x3 = fmaxf(s[6], s[7]);
    float x4 = fmaxf(s[8], s[9]),  x5 = fmaxf(s[10], s[11]);
    float x6 = fmaxf(s[12], s[13]), x7 = fmaxf(s[14], s[15]);
    float pm = fmaxf(fmaxf(fmaxf(x0, x1), fmaxf(x2, x3)),
                     fmaxf(fmaxf(x4, x5), fmaxf(x6, x7)));
    pm = fmaxf(pm, __shfl_xor(pm, 32));

    if (!__all(pm - m <= 8.0f)){       // defer-max: rescale only on real growth
      float mn = fmaxf(m, pm);
      float corr = ex2(m - mn);
      if (hi == 0) corrw[w][lo] = corr;
      asm volatile("s_waitcnt lgkmcnt(0)" ::: "memory");
      f32x4 c0 = *reinterpret_cast<const f32x4*>(&corrw[w][(hi << 2)]);
      f32x4 c1 = *reinterpret_cast<const f32x4*>(&corrw[w][8 + (hi << 2)]);
      f32x4 c2 = *reinterpret_cast<const f32x4*>(&corrw[w][16 + (hi << 2)]);
      f32x4 c3 = *reinterpret_cast<const f32x4*>(&corrw[w][24 + (hi << 2)]);
#pragma unroll
      for (int r = 0; r < 4; r++){
        acc0[r]      *= c0[r]; acc1[r]      *= c0[r];
        acc0[4 + r]  *= c1[r]; acc1[4 + r]  *= c1[r];
        acc0[8 + r]  *= c2[r]; acc1[8 + r]  *= c2[r];
        acc0[12 + r] *= c3[r]; acc1[12 + r] *= c3[r];
      }
      ls *= corr;
      m = mn;
    }

#pragma unroll
    for (int r = 0; r < 16; r++) s[r] = ex2(s[r] - m);   // P (masked -> 0)

    float y0 = s[0]+s[1], y1 = s[2]+s[3], y2 = s[4]+s[5], y3 = s[6]+s[7];
    float y4 = s[8]+s[9], y5 = s[10]+s[11], y6 = s[12]+s[13], y7 = s[14]+s[15];
    float rs = ((y0+y1)+(y2+y3)) + ((y4+y5)+(y6+y7));
    rs += __shfl_xor(rs, 32);
    ls += rs;

    // pack P -> bf16 pairs; build PV A-frags via hi<->lo exchange (k ascending)
    unsigned pk0 = bfpack(s[0], s[1]),   pk1 = bfpack(s[2], s[3]);
    unsigned pk2 = bfpack(s[4], s[5]),   pk3 = bfpack(s[6], s[7]);
    unsigned pk4 = bfpack(s[8], s[9]),   pk5 = bfpack(s[10], s[11]);
    unsigned pk6 = bfpack(s[12], s[13]), pk7 = bfpack(s[14], s[15]);

    unsigned sd0 = hi ? pk0 : pk2, sd1 = hi ? pk1 : pk3;
    unsigned rv0 = (unsigned)__shfl_xor((int)sd0, 32);
    unsigned rv1 = (unsigned)__shfl_xor((int)sd1, 32);
    union { s16x8 v; unsigned u[4]; } A0, A1;
    A0.u[0] = hi ? rv0 : pk0; A0.u[1] = hi ? rv1 : pk1;
    A0.u[2] = hi ? pk2 : rv0; A0.u[3] = hi ? pk3 : rv1;

    unsigned sd2 = hi ? pk4 : pk6, sd3 = hi ? pk5 : pk7;
    unsigned rv2 = (unsigned)__shfl_xor((int)sd2, 32);
    unsigned rv3 = (unsigned)__shfl_xor((int)sd3, 32);
    A1.u[0] = hi ? rv2 : pk4; A1.u[1] = hi ? rv3 : pk5;
    A1.u[2] = hi ? pk6 : rv2; A1.u[3] = hi ? pk7 : rv3;

    const short* vp = Vt + ((size_t)((b << 6) + lo)) * S_ + k0 + hi * 8;
    s16x8 v00 = *reinterpret_cast<const s16x8*>(vp);
    s16x8 v01 = *reinterpret_cast<const s16x8*>(vp + 16);
    s16x8 v10 = *reinterpret_cast<const s16x8*>(vp + (size_t)32 * S_);
    s16x8 v11 = *reinterpret_cast<const s16x8*>(vp + (size_t)32 * S_ + 16);

    acc0 = __builtin_amdgcn_mfma_f32_32x32x16_bf16(A0.v, v00, acc0, 0, 0, 0);
    acc0 = __builtin_amdgcn_mfma_f32_32x32x16_bf16(A1.v, v01, acc0, 0, 0, 0);
    acc1 = __builtin_amdgcn_mfma_f32_32x32x16_bf16(A0.v, v10, acc1, 0, 0, 0);
    acc1 = __builtin_amdgcn_mfma_f32_32x32x16_bf16(A1.v, v11, acc1, 0, 0, 0);
  }

  // stash partials; O D-layout rows are queries
#pragma unroll
  for (int r = 0; r < 16; r++){
    int q = (r & 3) + ((r >> 2) << 3) + (hi << 2);
    accw[w][q][lo]      = acc0[r];
    accw[w][q][32 + lo] = acc1[r];
  }
  if (hi == 0){ mlw[w][lo][0] = m; mlw[w][lo][1] = ls; }
  __syncthreads();

  // merge 8 waves: 512 threads = 32 q x 16 d-groups of 4
  {
    int q  = tid >> 4;
    int dg = (tid & 15) << 2;
    float M = mlw[0][q][0];
#pragma unroll
    for (int j = 1; j < 8; j++) M = fmaxf(M, mlw[j][q][0]);
    float L = 0.f;
    f32x4 o = (f32x4){0.f,0.f,0.f,0.f};
#pragma unroll
    for (int j = 0; j < 8; j++){
      float wt = ex2(mlw[j][q][0] - M);
      L += mlw[j][q][1] * wt;
      f32x4 a = *reinterpret_cast<const f32x4*>(&accw[j][q][dg]);
      o += a * wt;
    }
    f32x4 res = o * (1.f / L);
    *reinterpret_cast<f32x4*>(out + ((size_t)((b << 12) + q0 + q)) * D_ + dg) = res;
  }
}

extern "C" void kernel_launch(void* const* d_in, const int* in_sizes, int n_in,
                              void* d_out, int out_size, void* d_ws, size_t ws_size,
                              hipStream_t stream){
  const float* X  = (const float*)d_in[0];
  const float* Wq = (const float*)d_in[1];
  const float* bq = (const float*)d_in[2];
  const float* Wk = (const float*)d_in[3];
  const float* bk = (const float*)d_in[4];
  const float* Wv = (const float*)d_in[5];
  const float* bv = (const float*)d_in[6];
  float* out = (float*)d_out;

  char* base = (char*)d_ws;
  short* Wt = (short*)(base);                    // 192*512*2      = 196608
  short* Qb = (short*)(base + 196608);           // 16384*64*2     = 2097152
  short* Kb = (short*)(base + 196608 + 2097152);
  short* Vt = (short*)(base + 196608 + 2 * 2097152);

  prep_kernel<<<384, 256, 0, stream>>>(Wq, Wk, Wv, Wt);
  proj_kernel<<<1024, 256, 0, stream>>>(X, Wt, bq, bk, bv, Qb, Kb, Vt);
  attn_kernel<<<512, 512, 0, stream>>>(Qb, Kb, Vt, out);
}

// Round 3
// 146.410 us; speedup vs baseline: 1.5549x; 1.2384x over previous
//
#include <hip/hip_runtime.h>
#include <hip/hip_bf16.h>

#define B_ 4
#define S_ 4096
#define E_ 512
#define D_ 64

typedef float  f32x4  __attribute__((ext_vector_type(4)));
typedef float  f32x16 __attribute__((ext_vector_type(16)));
typedef short  s16x8  __attribute__((ext_vector_type(8)));

__device__ inline short f2bf(float f){
  unsigned u = __builtin_bit_cast(unsigned, f);
  u += 0x7fffu + ((u >> 16) & 1u);
  return (short)(u >> 16);
}
__device__ inline unsigned bfpack(float a, float b){
  unsigned ua = __builtin_bit_cast(unsigned, a);
  unsigned ub = __builtin_bit_cast(unsigned, b);
  ua += 0x7fffu + ((ua >> 16) & 1u);
  ub += 0x7fffu + ((ub >> 16) & 1u);
  return (ua >> 16) | (ub & 0xffff0000u);
}
__device__ inline float ex2(float x){ return __builtin_amdgcn_exp2f(x); }

#define QSCALE 0.18033688f  // 0.125 * log2(e): softmax in exp2 domain, folded into Q

// Fragment-major layouts (shorts):
//   Qf/Kf[b][tile][N=4][lane=64][8] : elem = Q[b][tile*32 + lo][N*16 + hi*8 + j], lane = hi*32+lo
//   Vf   [b][tile][f=4][lane=64][8] : f = kh + 2*half;
//        elem = V[b][tile*32 + kh*16 + hi*8 + j][half*32 + lo]
// Each fragment = 512 shorts; each tile = 2048 shorts (4 KB).

// ---------------- prep: Wt[192][512] bf16 (row n = output col; 0..63 Q, 64..127 K, 128..191 V)
__global__ __launch_bounds__(256) void prep_kernel(const float* __restrict__ Wq,
                                                   const float* __restrict__ Wk,
                                                   const float* __restrict__ Wv,
                                                   short* __restrict__ Wt){
  int t = blockIdx.x * 256 + threadIdx.x;      // 0..98303
  int n = t >> 9, k = t & 511;
  const float* W = (n < 64) ? Wq : (n < 128 ? Wk : Wv);
  float v = W[k * 64 + (n & 63)];
  if (n < 64) v *= QSCALE;
  Wt[t] = f2bf(v);
}

// ---------------- proj: 1024 blocks, 1 block = 16-row tile; 4 waves split 192 cols (48 each).
__global__ __launch_bounds__(256) void proj_kernel(const float* __restrict__ X,
                                                   const short* __restrict__ Wt,
                                                   const float* __restrict__ bq,
                                                   const float* __restrict__ bk,
                                                   const float* __restrict__ bv,
                                                   short* __restrict__ Qf,
                                                   short* __restrict__ Kf,
                                                   short* __restrict__ Vf){
  int l = threadIdx.x & 63, w = threadIdx.x >> 6;
  int r0 = blockIdx.x * 16;
  int g = l >> 4, c = l & 15;

  f32x4 acc[3];
#pragma unroll
  for (int j = 0; j < 3; j++) acc[j] = (f32x4){0.f,0.f,0.f,0.f};

  const float* xp = X + (size_t)(r0 + c) * E_ + g * 8;
  const short* wp = Wt + (size_t)(w * 48 + c) * E_ + g * 8;

  for (int kk = 0; kk < 16; kk++){
    f32x4 a0 = *reinterpret_cast<const f32x4*>(xp + kk * 32);
    f32x4 a1 = *reinterpret_cast<const f32x4*>(xp + kk * 32 + 4);
    s16x8 af;
#pragma unroll
    for (int i = 0; i < 4; i++){ af[i] = f2bf(a0[i]); af[4+i] = f2bf(a1[i]); }
#pragma unroll
    for (int j = 0; j < 3; j++){
      s16x8 bf = *reinterpret_cast<const s16x8*>(wp + (size_t)j * 16 * E_ + kk * 32);
      acc[j] = __builtin_amdgcn_mfma_f32_16x16x32_bf16(af, bf, acc[j], 0, 0, 0);
    }
  }

#pragma unroll
  for (int j = 0; j < 3; j++){
    int cbi = w * 3 + j;
    int d = ((cbi & 3) << 4) + c;              // output col within Q/K/V (0..63)
    float bias = (cbi < 4) ? bq[d] * QSCALE : (cbi < 8 ? bk[d] : bv[d]);
#pragma unroll
    for (int r = 0; r < 4; r++){
      int T  = r0 + g * 4 + r;                 // global token
      int b  = T >> 12;
      int Tb = T & 4095;
      short h = f2bf(acc[j][r] + bias);
      if (cbi < 8){
        // Q/K fragment-major: ((b*128+t)*4 + N)*512 + hi*256 + lo*8 + j
        size_t a = (((size_t)(b * 128 + (Tb >> 5)) * 4 + (d >> 4)) << 9)
                 + (((d >> 3) & 1) << 8) + ((Tb & 31) << 3) + (d & 7);
        if (cbi < 4) Qf[a] = h; else Kf[a] = h;
      } else {
        // V: f = kh + 2*half ; lane = (hi from token)*32 + (d&31) ; j = token&7
        size_t a = (((size_t)(b * 128 + (Tb >> 5)) * 4
                     + (((Tb >> 4) & 1) + ((d >> 5) << 1))) << 9)
                 + (((Tb >> 3) & 1) << 8) + ((d & 31) << 3) + (Tb & 7);
        Vf[a] = h;
      }
    }
  }
}

// ---------------- attn: 32x32 swapped-QK^T flash. 512 blocks (b,tile) x 8 waves (keys mod 8).
// All operand loads are fragment-major: base + lane*16B, fully coalesced.
__global__ __launch_bounds__(512, 4) void attn_kernel(const short* __restrict__ Qf,
                                                      const short* __restrict__ Kf,
                                                      const short* __restrict__ Vf,
                                                      float* __restrict__ out){
  __shared__ float accw[8][32][64];   // 64 KB: per-wave partial O (f32)
  __shared__ float mlw[8][32][2];     // 2 KB: per-wave (m, l) per query
  __shared__ float corrw[8][32];      // 1 KB: rescale-factor bounce (rare path)

  const int tid = threadIdx.x;
  const int w  = tid >> 6;
  const int l  = tid & 63;
  const int lo = l & 31, hi = l >> 5;
  const int bid = blockIdx.x;
  const int b  = bid >> 7;
  const int t  = 127 - (bid & 127);   // heavy tiles first
  const int q0 = t << 5;

  const short* qb = Qf + (((size_t)(b * 128 + t)) << 11) + (l << 3);
  s16x8 qf0 = *reinterpret_cast<const s16x8*>(qb);
  s16x8 qf1 = *reinterpret_cast<const s16x8*>(qb + 512);
  s16x8 qf2 = *reinterpret_cast<const s16x8*>(qb + 1024);
  s16x8 qf3 = *reinterpret_cast<const s16x8*>(qb + 1536);

  float m = -1e30f, ls = 0.f;
  f32x16 acc0, acc1;
#pragma unroll
  for (int r = 0; r < 16; r++){ acc0[r] = 0.f; acc1[r] = 0.f; }

  const int nkt = t + 1;
  for (int kt = w; kt < nkt; kt += 8){
    const int k0 = kt << 5;
    const short* kb = Kf + (((size_t)(b * 128 + kt)) << 11) + (l << 3);
    s16x8 kf0 = *reinterpret_cast<const s16x8*>(kb);
    s16x8 kf1 = *reinterpret_cast<const s16x8*>(kb + 512);
    s16x8 kf2 = *reinterpret_cast<const s16x8*>(kb + 1024);
    s16x8 kf3 = *reinterpret_cast<const s16x8*>(kb + 1536);
    // V in flight during QK^T + softmax
    const short* vb = Vf + (((size_t)(b * 128 + kt)) << 11) + (l << 3);
    s16x8 v00 = *reinterpret_cast<const s16x8*>(vb);          // keys 0-15, d 0-31
    s16x8 v01 = *reinterpret_cast<const s16x8*>(vb + 512);    // keys 16-31, d 0-31
    s16x8 v10 = *reinterpret_cast<const s16x8*>(vb + 1024);   // keys 0-15, d 32-63
    s16x8 v11 = *reinterpret_cast<const s16x8*>(vb + 1536);   // keys 16-31, d 32-63

    f32x16 s;
#pragma unroll
    for (int r = 0; r < 16; r++) s[r] = 0.f;
    s = __builtin_amdgcn_mfma_f32_32x32x16_bf16(kf0, qf0, s, 0, 0, 0);
    s = __builtin_amdgcn_mfma_f32_32x32x16_bf16(kf1, qf1, s, 0, 0, 0);
    s = __builtin_amdgcn_mfma_f32_32x32x16_bf16(kf2, qf2, s, 0, 0, 0);
    s = __builtin_amdgcn_mfma_f32_32x32x16_bf16(kf3, qf3, s, 0, 0, 0);
    // D: col(lane&31)=query, row=(r&3)+8*(r>>2)+4*hi = key offset

    if (k0 == q0){                     // only the diagonal tile needs masking
#pragma unroll
      for (int r = 0; r < 16; r++){
        int key = (r & 3) + ((r >> 2) << 3) + (hi << 2);
        if (key > lo) s[r] = -1e30f;
      }
    }

    // lane-local row max + pair exchange
    float x0 = fmaxf(s[0], s[1]),  x1 = fmaxf(s[2], s[3]);
    float x2 = fmaxf(s[4], s[5]),  x3 = fmaxf(s[6], s[7]);
    float x4 = fmaxf(s[8], s[9]),  x5 = fmaxf(s[10], s[11]);
    float x6 = fmaxf(s[12], s[13]), x7 = fmaxf(s[14], s[15]);
    float pm = fmaxf(fmaxf(fmaxf(x0, x1), fmaxf(x2, x3)),
                     fmaxf(fmaxf(x4, x5), fmaxf(x6, x7)));
    pm = fmaxf(pm, __shfl_xor(pm, 32));

    if (!__all(pm - m <= 8.0f)){       // defer-max: rescale only on real growth
      float mn = fmaxf(m, pm);
      float corr = ex2(m - mn);
      if (hi == 0) corrw[w][lo] = corr;
      asm volatile("s_waitcnt lgkmcnt(0)" ::: "memory");
      __builtin_amdgcn_sched_barrier(0);
      f32x4 c0 = *reinterpret_cast<const f32x4*>(&corrw[w][(hi << 2)]);
      f32x4 c1 = *reinterpret_cast<const f32x4*>(&corrw[w][8 + (hi << 2)]);
      f32x4 c2 = *reinterpret_cast<const f32x4*>(&corrw[w][16 + (hi << 2)]);
      f32x4 c3 = *reinterpret_cast<const f32x4*>(&corrw[w][24 + (hi << 2)]);
#pragma unroll
      for (int r = 0; r < 4; r++){
        acc0[r]      *= c0[r]; acc1[r]      *= c0[r];
        acc0[4 + r]  *= c1[r]; acc1[4 + r]  *= c1[r];
        acc0[8 + r]  *= c2[r]; acc1[8 + r]  *= c2[r];
        acc0[12 + r] *= c3[r]; acc1[12 + r] *= c3[r];
      }
      ls *= corr;
      m = mn;
    }

#pragma unroll
    for (int r = 0; r < 16; r++) s[r] = ex2(s[r] - m);   // P (masked -> 0)

    float y0 = s[0]+s[1], y1 = s[2]+s[3], y2 = s[4]+s[5], y3 = s[6]+s[7];
    float y4 = s[8]+s[9], y5 = s[10]+s[11], y6 = s[12]+s[13], y7 = s[14]+s[15];
    float rs = ((y0+y1)+(y2+y3)) + ((y4+y5)+(y6+y7));
    rs += __shfl_xor(rs, 32);
    ls += rs;

    // pack P -> bf16 pairs; build PV A-frags via hi<->lo exchange (k ascending)
    unsigned pk0 = bfpack(s[0], s[1]),   pk1 = bfpack(s[2], s[3]);
    unsigned pk2 = bfpack(s[4], s[5]),   pk3 = bfpack(s[6], s[7]);
    unsigned pk4 = bfpack(s[8], s[9]),   pk5 = bfpack(s[10], s[11]);
    unsigned pk6 = bfpack(s[12], s[13]), pk7 = bfpack(s[14], s[15]);

    unsigned sd0 = hi ? pk0 : pk2, sd1 = hi ? pk1 : pk3;
    unsigned rv0 = (unsigned)__shfl_xor((int)sd0, 32);
    unsigned rv1 = (unsigned)__shfl_xor((int)sd1, 32);
    union { s16x8 v; unsigned u[4]; } A0, A1;
    A0.u[0] = hi ? rv0 : pk0; A0.u[1] = hi ? rv1 : pk1;
    A0.u[2] = hi ? pk2 : rv0; A0.u[3] = hi ? pk3 : rv1;

    unsigned sd2 = hi ? pk4 : pk6, sd3 = hi ? pk5 : pk7;
    unsigned rv2 = (unsigned)__shfl_xor((int)sd2, 32);
    unsigned rv3 = (unsigned)__shfl_xor((int)sd3, 32);
    A1.u[0] = hi ? rv2 : pk4; A1.u[1] = hi ? rv3 : pk5;
    A1.u[2] = hi ? pk6 : rv2; A1.u[3] = hi ? pk7 : rv3;

    acc0 = __builtin_amdgcn_mfma_f32_32x32x16_bf16(A0.v, v00, acc0, 0, 0, 0);
    acc0 = __builtin_amdgcn_mfma_f32_32x32x16_bf16(A1.v, v01, acc0, 0, 0, 0);
    acc1 = __builtin_amdgcn_mfma_f32_32x32x16_bf16(A0.v, v10, acc1, 0, 0, 0);
    acc1 = __builtin_amdgcn_mfma_f32_32x32x16_bf16(A1.v, v11, acc1, 0, 0, 0);
  }

  // stash partials; O D-layout rows are queries
#pragma unroll
  for (int r = 0; r < 16; r++){
    int q = (r & 3) + ((r >> 2) << 3) + (hi << 2);
    accw[w][q][lo]      = acc0[r];
    accw[w][q][32 + lo] = acc1[r];
  }
  if (hi == 0){ mlw[w][lo][0] = m; mlw[w][lo][1] = ls; }
  __syncthreads();

  // merge 8 waves: 512 threads = 32 q x 16 d-groups of 4
  {
    int q  = tid >> 4;
    int dg = (tid & 15) << 2;
    float M = mlw[0][q][0];
#pragma unroll
    for (int j = 1; j < 8; j++) M = fmaxf(M, mlw[j][q][0]);
    float L = 0.f;
    f32x4 o = (f32x4){0.f,0.f,0.f,0.f};
#pragma unroll
    for (int j = 0; j < 8; j++){
      float wt = ex2(mlw[j][q][0] - M);
      L += mlw[j][q][1] * wt;
      f32x4 a = *reinterpret_cast<const f32x4*>(&accw[j][q][dg]);
      o += a * wt;
    }
    f32x4 res = o * (1.f / L);
    *reinterpret_cast<f32x4*>(out + ((size_t)((b << 12) + q0 + q)) * D_ + dg) = res;
  }
}

extern "C" void kernel_launch(void* const* d_in, const int* in_sizes, int n_in,
                              void* d_out, int out_size, void* d_ws, size_t ws_size,
                              hipStream_t stream){
  const float* X  = (const float*)d_in[0];
  const float* Wq = (const float*)d_in[1];
  const float* bq = (const float*)d_in[2];
  const float* Wk = (const float*)d_in[3];
  const float* bk = (const float*)d_in[4];
  const float* Wv = (const float*)d_in[5];
  const float* bv = (const float*)d_in[6];
  float* out = (float*)d_out;

  char* base = (char*)d_ws;
  short* Wt = (short*)(base);                    // 192*512*2      = 196608
  short* Qf = (short*)(base + 196608);           // 4*128*2048*2   = 2097152
  short* Kf = (short*)(base + 196608 + 2097152);
  short* Vf = (short*)(base + 196608 + 2 * 2097152);

  prep_kernel<<<384, 256, 0, stream>>>(Wq, Wk, Wv, Wt);
  proj_kernel<<<1024, 256, 0, stream>>>(X, Wt, bq, bk, bv, Qf, Kf, Vf);
  attn_kernel<<<512, 512, 0, stream>>>(Qf, Kf, Vf, out);
}

// Round 5
// 120.665 us; speedup vs baseline: 1.8866x; 1.2134x over previous
//
#include <hip/hip_runtime.h>
#include <hip/hip_bf16.h>

#define B_ 4
#define S_ 4096
#define E_ 512
#define D_ 64

typedef float  f32x4  __attribute__((ext_vector_type(4)));
typedef float  f32x16 __attribute__((ext_vector_type(16)));
typedef short  s16x8  __attribute__((ext_vector_type(8)));

__device__ inline short f2bf(float f){
  unsigned u = __builtin_bit_cast(unsigned, f);
  u += 0x7fffu + ((u >> 16) & 1u);
  return (short)(u >> 16);
}
__device__ inline unsigned bfpack(float a, float b){
  unsigned ua = __builtin_bit_cast(unsigned, a);
  unsigned ub = __builtin_bit_cast(unsigned, b);
  ua += 0x7fffu + ((ua >> 16) & 1u);
  ub += 0x7fffu + ((ub >> 16) & 1u);
  return (ua >> 16) | (ub & 0xffff0000u);
}
__device__ inline float ex2(float x){ return __builtin_amdgcn_exp2f(x); }

#define QSCALE 0.18033688f  // 0.125 * log2(e): softmax in exp2 domain, folded into Q

// Fragment-major layouts (shorts):
//   Wtf[cbi 12][kk 16][lane 64][8] : elem = Wcol(n=cbi*16+(l&15))[k=kk*32+(l>>4)*8+j]
//   Qf/Kf[b][tile][N=4][lane=64][8]: elem = Q[b][tile*32+lo][N*16+hi*8+j], lane=hi*32+lo
//   Vf   [b][tile][f=4][lane=64][8]: f=kh+2*half; elem = V[b][tile*32+kh*16+hi*8+j][half*32+lo]
// Every MFMA operand load in proj/attn = base + lane*16B (one coalesced transaction).

// ---------------- prep: build Wtf fragment-major
__global__ __launch_bounds__(256) void prep_kernel(const float* __restrict__ Wq,
                                                   const float* __restrict__ Wk,
                                                   const float* __restrict__ Wv,
                                                   short* __restrict__ Wtf){
  int o = blockIdx.x * 256 + threadIdx.x;      // 0..98303
  int cbi = o >> 13;
  int l   = (o >> 3) & 63;
  int j   = o & 7;
  int kk  = (o >> 9) & 15;
  int n = cbi * 16 + (l & 15);
  int k = kk * 32 + (l >> 4) * 8 + j;
  const float* W = (n < 64) ? Wq : (n < 128 ? Wk : Wv);
  float v = W[k * 64 + (n & 63)];
  if (n < 64) v *= QSCALE;
  Wtf[o] = f2bf(v);
}

// ---------------- proj: 1024 blocks x 256 thr (4 waves). Block = 16-row tile of X.
// Phase1: coalesced X -> swizzled LDS bf16. Phase2: MFMA (A from LDS, B from Wtf coalesced).
// Phase3: results -> LDS (Os row-major, OsT col-major), gather -> fragment-major Q/K/V.
__global__ __launch_bounds__(256) void proj_kernel(const float* __restrict__ X,
                                                   const short* __restrict__ Wtf,
                                                   const float* __restrict__ bq,
                                                   const float* __restrict__ bk,
                                                   const float* __restrict__ bv,
                                                   short* __restrict__ Qf,
                                                   short* __restrict__ Kf,
                                                   short* __restrict__ Vf){
  __shared__ short Xs[1024 * 8];      // 16 KB: granule (row*64 + (gr^(row&7)))*8
  __shared__ short Os[16][136];       // Q cols 0-63, K cols 64-127 (row stride 272B, 16B-aligned)
  __shared__ short OsT[64][24];       // V transposed: OsT[vcol][row] (row stride 48B)

  const int tid = threadIdx.x;
  const int l = tid & 63, w = tid >> 6;
  const int c = l & 15,  g = l >> 4;
  const int r0 = blockIdx.x * 16;
  const int t  = (r0 >> 5) & 127;     // 32-token tile index WITHIN batch (bug fix: was r0>>5 global)
  const int h  = (r0 >> 4) & 1;       // which half of the tile
  const int b  = r0 >> 12;

  // ---- phase 1: stage X tile (16 x 512 f32) as bf16, swizzled
#pragma unroll
  for (int i = 0; i < 4; i++){
    int ch  = i * 256 + tid;          // 0..1023 granules
    int row = ch >> 6, gr = ch & 63;
    const float* xp = X + (size_t)(r0 + row) * E_ + gr * 8;
    f32x4 a0 = *reinterpret_cast<const f32x4*>(xp);
    f32x4 a1 = *reinterpret_cast<const f32x4*>(xp + 4);
    s16x8 hv;
#pragma unroll
    for (int q = 0; q < 4; q++){ hv[q] = f2bf(a0[q]); hv[4+q] = f2bf(a1[q]); }
    *reinterpret_cast<s16x8*>(&Xs[(row * 64 + (gr ^ (row & 7))) * 8]) = hv;
  }
  __syncthreads();

  // ---- phase 2: 3 col-blocks per wave, 16 k-steps
  f32x4 acc[3];
#pragma unroll
  for (int j = 0; j < 3; j++) acc[j] = (f32x4){0.f,0.f,0.f,0.f};

  for (int kk = 0; kk < 16; kk++){
    s16x8 af = *reinterpret_cast<const s16x8*>(&Xs[(c * 64 + ((kk * 4 + g) ^ (c & 7))) * 8]);
#pragma unroll
    for (int j = 0; j < 3; j++){
      int cbi = w * 3 + j;
      s16x8 bf = *reinterpret_cast<const s16x8*>(Wtf + (((size_t)(cbi * 16 + kk)) << 9) + (l << 3));
      acc[j] = __builtin_amdgcn_mfma_f32_16x16x32_bf16(af, bf, acc[j], 0, 0, 0);
    }
  }

  // ---- phase 3a: epilogue -> LDS
#pragma unroll
  for (int j = 0; j < 3; j++){
    int cbi = w * 3 + j;
    int d = ((cbi & 3) << 4) + c;     // col within Q/K/V
    if (cbi < 8){
      float bias = (cbi < 4) ? bq[d] * QSCALE : bk[d];
      int col = (cbi < 4) ? d : (64 + d);
#pragma unroll
      for (int r = 0; r < 4; r++) Os[g * 4 + r][col] = f2bf(acc[j][r] + bias);
    } else {
      float bias = bv[d];
      union { unsigned long long u; short s[4]; } pk;
#pragma unroll
      for (int r = 0; r < 4; r++) pk.s[r] = f2bf(acc[j][r] + bias);
      *reinterpret_cast<unsigned long long*>(&OsT[d][g * 4]) = pk.u;
    }
  }
  __syncthreads();

  // ---- phase 3b: gather -> fragment-major global (coalesced 16B stores)
  const size_t tbase = ((size_t)(b * 128 + t)) << 11;
  {
    int q = tid & 127;
    int N = q >> 5, hd = (q >> 4) & 1, lo16 = q & 15;
    int d0 = N * 16 + hd * 8;
    int col = (tid < 128) ? d0 : (64 + d0);
    s16x8 vv = *reinterpret_cast<const s16x8*>(&Os[lo16][col]);
    short* dst = (tid < 128 ? Qf : Kf) + tbase + N * 512 + hd * 256 + (h * 16 + lo16) * 8;
    *reinterpret_cast<s16x8*>(dst) = vv;
  }
  if (tid < 128){
    int hf = tid >> 6, ht = (tid >> 5) & 1, dl = tid & 31;
    s16x8 vv = *reinterpret_cast<const s16x8*>(&OsT[hf * 32 + dl][ht * 8]);
    short* dst = Vf + tbase + (h + 2 * hf) * 512 + ht * 256 + dl * 8;
    *reinterpret_cast<s16x8*>(dst) = vv;
  }
}

// ---------------- attn: 32x32 swapped-QK^T flash. 512 blocks (b,tile) x 8 waves (keys mod 8).
// All operand loads are fragment-major: base + lane*16B, fully coalesced.
__global__ __launch_bounds__(512, 4) void attn_kernel(const short* __restrict__ Qf,
                                                      const short* __restrict__ Kf,
                                                      const short* __restrict__ Vf,
                                                      float* __restrict__ out){
  __shared__ float accw[8][32][64];   // 64 KB: per-wave partial O (f32)
  __shared__ float mlw[8][32][2];     // 2 KB: per-wave (m, l) per query
  __shared__ float corrw[8][32];      // 1 KB: rescale-factor bounce (rare path)

  const int tid = threadIdx.x;
  const int w  = tid >> 6;
  const int l  = tid & 63;
  const int lo = l & 31, hi = l >> 5;
  const int bid = blockIdx.x;
  const int b  = bid >> 7;
  const int t  = 127 - (bid & 127);   // heavy tiles first
  const int q0 = t << 5;

  const short* qb = Qf + (((size_t)(b * 128 + t)) << 11) + (l << 3);
  s16x8 qf0 = *reinterpret_cast<const s16x8*>(qb);
  s16x8 qf1 = *reinterpret_cast<const s16x8*>(qb + 512);
  s16x8 qf2 = *reinterpret_cast<const s16x8*>(qb + 1024);
  s16x8 qf3 = *reinterpret_cast<const s16x8*>(qb + 1536);

  float m = -1e30f, ls = 0.f;
  f32x16 acc0, acc1;
#pragma unroll
  for (int r = 0; r < 16; r++){ acc0[r] = 0.f; acc1[r] = 0.f; }

  const int nkt = t + 1;
  for (int kt = w; kt < nkt; kt += 8){
    const int k0 = kt << 5;
    const short* kb = Kf + (((size_t)(b * 128 + kt)) << 11) + (l << 3);
    s16x8 kf0 = *reinterpret_cast<const s16x8*>(kb);
    s16x8 kf1 = *reinterpret_cast<const s16x8*>(kb + 512);
    s16x8 kf2 = *reinterpret_cast<const s16x8*>(kb + 1024);
    s16x8 kf3 = *reinterpret_cast<const s16x8*>(kb + 1536);
    const short* vb = Vf + (((size_t)(b * 128 + kt)) << 11) + (l << 3);
    s16x8 v00 = *reinterpret_cast<const s16x8*>(vb);          // keys 0-15, d 0-31
    s16x8 v01 = *reinterpret_cast<const s16x8*>(vb + 512);    // keys 16-31, d 0-31
    s16x8 v10 = *reinterpret_cast<const s16x8*>(vb + 1024);   // keys 0-15, d 32-63
    s16x8 v11 = *reinterpret_cast<const s16x8*>(vb + 1536);   // keys 16-31, d 32-63

    f32x16 s;
#pragma unroll
    for (int r = 0; r < 16; r++) s[r] = 0.f;
    s = __builtin_amdgcn_mfma_f32_32x32x16_bf16(kf0, qf0, s, 0, 0, 0);
    s = __builtin_amdgcn_mfma_f32_32x32x16_bf16(kf1, qf1, s, 0, 0, 0);
    s = __builtin_amdgcn_mfma_f32_32x32x16_bf16(kf2, qf2, s, 0, 0, 0);
    s = __builtin_amdgcn_mfma_f32_32x32x16_bf16(kf3, qf3, s, 0, 0, 0);
    // D: col(lane&31)=query, row=(r&3)+8*(r>>2)+4*hi = key offset

    if (k0 == q0){                     // only the diagonal tile needs masking
#pragma unroll
      for (int r = 0; r < 16; r++){
        int key = (r & 3) + ((r >> 2) << 3) + (hi << 2);
        if (key > lo) s[r] = -1e30f;
      }
    }

    // lane-local row max + pair exchange
    float x0 = fmaxf(s[0], s[1]),  x1 = fmaxf(s[2], s[3]);
    float x2 = fmaxf(s[4], s[5]),  x3 = fmaxf(s[6], s[7]);
    float x4 = fmaxf(s[8], s[9]),  x5 = fmaxf(s[10], s[11]);
    float x6 = fmaxf(s[12], s[13]), x7 = fmaxf(s[14], s[15]);
    float pm = fmaxf(fmaxf(fmaxf(x0, x1), fmaxf(x2, x3)),
                     fmaxf(fmaxf(x4, x5), fmaxf(x6, x7)));
    pm = fmaxf(pm, __shfl_xor(pm, 32));

    if (!__all(pm - m <= 8.0f)){       // defer-max: rescale only on real growth
      float mn = fmaxf(m, pm);
      float corr = ex2(m - mn);
      if (hi == 0) corrw[w][lo] = corr;
      asm volatile("s_waitcnt lgkmcnt(0)" ::: "memory");
      __builtin_amdgcn_sched_barrier(0);
      f32x4 c0 = *reinterpret_cast<const f32x4*>(&corrw[w][(hi << 2)]);
      f32x4 c1 = *reinterpret_cast<const f32x4*>(&corrw[w][8 + (hi << 2)]);
      f32x4 c2 = *reinterpret_cast<const f32x4*>(&corrw[w][16 + (hi << 2)]);
      f32x4 c3 = *reinterpret_cast<const f32x4*>(&corrw[w][24 + (hi << 2)]);
#pragma unroll
      for (int r = 0; r < 4; r++){
        acc0[r]      *= c0[r]; acc1[r]      *= c0[r];
        acc0[4 + r]  *= c1[r]; acc1[4 + r]  *= c1[r];
        acc0[8 + r]  *= c2[r]; acc1[8 + r]  *= c2[r];
        acc0[12 + r] *= c3[r]; acc1[12 + r] *= c3[r];
      }
      ls *= corr;
      m = mn;
    }

#pragma unroll
    for (int r = 0; r < 16; r++) s[r] = ex2(s[r] - m);   // P (masked -> 0)

    float y0 = s[0]+s[1], y1 = s[2]+s[3], y2 = s[4]+s[5], y3 = s[6]+s[7];
    float y4 = s[8]+s[9], y5 = s[10]+s[11], y6 = s[12]+s[13], y7 = s[14]+s[15];
    float rs = ((y0+y1)+(y2+y3)) + ((y4+y5)+(y6+y7));
    rs += __shfl_xor(rs, 32);
    ls += rs;

    // pack P -> bf16 pairs; build PV A-frags via hi<->lo exchange (k ascending)
    unsigned pk0 = bfpack(s[0], s[1]),   pk1 = bfpack(s[2], s[3]);
    unsigned pk2 = bfpack(s[4], s[5]),   pk3 = bfpack(s[6], s[7]);
    unsigned pk4 = bfpack(s[8], s[9]),   pk5 = bfpack(s[10], s[11]);
    unsigned pk6 = bfpack(s[12], s[13]), pk7 = bfpack(s[14], s[15]);

    unsigned sd0 = hi ? pk0 : pk2, sd1 = hi ? pk1 : pk3;
    unsigned rv0 = (unsigned)__shfl_xor((int)sd0, 32);
    unsigned rv1 = (unsigned)__shfl_xor((int)sd1, 32);
    union { s16x8 v; unsigned u[4]; } A0, A1;
    A0.u[0] = hi ? rv0 : pk0; A0.u[1] = hi ? rv1 : pk1;
    A0.u[2] = hi ? pk2 : rv0; A0.u[3] = hi ? pk3 : rv1;

    unsigned sd2 = hi ? pk4 : pk6, sd3 = hi ? pk5 : pk7;
    unsigned rv2 = (unsigned)__shfl_xor((int)sd2, 32);
    unsigned rv3 = (unsigned)__shfl_xor((int)sd3, 32);
    A1.u[0] = hi ? rv2 : pk4; A1.u[1] = hi ? rv3 : pk5;
    A1.u[2] = hi ? pk6 : rv2; A1.u[3] = hi ? pk7 : rv3;

    acc0 = __builtin_amdgcn_mfma_f32_32x32x16_bf16(A0.v, v00, acc0, 0, 0, 0);
    acc0 = __builtin_amdgcn_mfma_f32_32x32x16_bf16(A1.v, v01, acc0, 0, 0, 0);
    acc1 = __builtin_amdgcn_mfma_f32_32x32x16_bf16(A0.v, v10, acc1, 0, 0, 0);
    acc1 = __builtin_amdgcn_mfma_f32_32x32x16_bf16(A1.v, v11, acc1, 0, 0, 0);
  }

  // stash partials; O D-layout rows are queries
#pragma unroll
  for (int r = 0; r < 16; r++){
    int q = (r & 3) + ((r >> 2) << 3) + (hi << 2);
    accw[w][q][lo]      = acc0[r];
    accw[w][q][32 + lo] = acc1[r];
  }
  if (hi == 0){ mlw[w][lo][0] = m; mlw[w][lo][1] = ls; }
  __syncthreads();

  // merge 8 waves: 512 threads = 32 q x 16 d-groups of 4
  {
    int q  = tid >> 4;
    int dg = (tid & 15) << 2;
    float M = mlw[0][q][0];
#pragma unroll
    for (int j = 1; j < 8; j++) M = fmaxf(M, mlw[j][q][0]);
    float L = 0.f;
    f32x4 o = (f32x4){0.f,0.f,0.f,0.f};
#pragma unroll
    for (int j = 0; j < 8; j++){
      float wt = ex2(mlw[j][q][0] - M);
      L += mlw[j][q][1] * wt;
      f32x4 a = *reinterpret_cast<const f32x4*>(&accw[j][q][dg]);
      o += a * wt;
    }
    f32x4 res = o * (1.f / L);
    *reinterpret_cast<f32x4*>(out + ((size_t)((b << 12) + q0 + q)) * D_ + dg) = res;
  }
}

extern "C" void kernel_launch(void* const* d_in, const int* in_sizes, int n_in,
                              void* d_out, int out_size, void* d_ws, size_t ws_size,
                              hipStream_t stream){
  const float* X  = (const float*)d_in[0];
  const float* Wq = (const float*)d_in[1];
  const float* bq = (const float*)d_in[2];
  const float* Wk = (const float*)d_in[3];
  const float* bk = (const float*)d_in[4];
  const float* Wv = (const float*)d_in[5];
  const float* bv = (const float*)d_in[6];
  float* out = (float*)d_out;

  char* base = (char*)d_ws;
  short* Wtf = (short*)(base);                   // 12*16*64*8*2   = 196608
  short* Qf  = (short*)(base + 196608);          // 4*128*2048*2   = 2097152
  short* Kf  = (short*)(base + 196608 + 2097152);
  short* Vf  = (short*)(base + 196608 + 2 * 2097152);

  prep_kernel<<<384, 256, 0, stream>>>(Wq, Wk, Wv, Wtf);
  proj_kernel<<<1024, 256, 0, stream>>>(X, Wtf, bq, bk, bv, Qf, Kf, Vf);
  attn_kernel<<<512, 512, 0, stream>>>(Qf, Kf, Vf, out);
}